// Round 5
// baseline (12632.993 us; speedup 1.0000x reference)
//
#include <hip/hip_runtime.h>
#include <math.h>

// GRU enc-dec w/ attention. B=32,S=512,T=128,V=128,L=5,E=512,H=1024,F=2048.
// R5: launch-per-step with MAX fusion (grid barrier lost to launch gaps in R4).
// Encoder: 1 kernel/step (GEMM via packed per-WG weight slices + gates inline).
// Decoder: 3 kernels/step (att+hc / ctxsm / gi+gh+gates fused). h bf16 double-
// buffered across steps; h fp32 carry is per-own-unit (no cross-block race).

#define Bb 32
#define Ss 512
#define Tt 128
#define Vv 128
#define Hh 1024
#define H3 3072
#define APAD 40

typedef __attribute__((ext_vector_type(8))) short bf16x8;
typedef __attribute__((ext_vector_type(4))) float f32x4;

__device__ inline f32x4 mfma_bf16(bf16x8 a, bf16x8 b, f32x4 c) {
  return __builtin_amdgcn_mfma_f32_16x16x32_bf16(a, b, c, 0, 0, 0);
}
__device__ inline unsigned short f2bf(float f) {
  unsigned u = __builtin_bit_cast(unsigned, f);
  unsigned r = (u + 0x7fffu + ((u >> 16) & 1u)) >> 16;
  return (unsigned short)r;
}
__device__ inline float lof(unsigned u) { return __builtin_bit_cast(float, u << 16); }
__device__ inline float hif(unsigned u) { return __builtin_bit_cast(float, u & 0xffff0000u); }
__device__ inline float bf2f(unsigned short h) {
  return __builtin_bit_cast(float, ((unsigned)h) << 16);
}

// ---------------- workspace offsets (BYTES) ----------------
#define O_ESBF   0UL            // es bf16      [B*S][1024]  32MB
#define O_ESQ    33554432UL     // esq bf16     [B*S][1024]  32MB  (aliased: G1 in MLP)
#define O_AVBF   67108864UL     // av bf16      [B*S][1024]  32MB  (aliased: G2 in MLP)
#define O_HCBF   100663296UL    // hc bf16      [T*B][1024]   8MB
#define O_WHE    109051904UL    // enc_Wh packed [32][96][1024] bf16  6MB
#define O_WHD    115343360UL    // dec_Wh packed 6MB
#define O_WIC    121634816UL    // dec_Wi ctx packed 6MB
#define O_WKB    127926272UL    // Wk bf16 [1024][1024] 2MB
#define O_WQT    130023424UL    // Wq^T bf16 [1024][1024] 2MB
#define O_W1B    132120576UL    // W1 bf16 [4096][1024] 8MB
#define O_W2B    140509184UL    // W2 bf16 [2048][4096] 16MB
#define O_W3B    157286400UL    // W3 bf16 [128][2048] 0.5MB
#define O_XCAT   157810688UL    // fp32 [640][1024]
#define O_EMBFC  160432128UL    // fp32 [640][512]
#define O_GITAB  161742848UL    // fp32 [640][1024][3] (packed r/z/n)
#define O_AVTAB  169607168UL    // fp32 [640][1024]
#define O_DGIXT  172228608UL    // fp32 [128][1024][3] (packed r/z/n)
#define O_H      174587904UL    // fp32 [32][1024]  (h carry, enc then dec)
#define O_HBF    174718976UL    // bf16 [32][1024]  h double-buf A
#define O_CTX    174784512UL    // fp32 [32][1024]
#define O_CTXBF  174915584UL    // bf16 [32][1024]
#define O_ATTL   174981120UL    // fp32 [32][512]
#define O_HB1    175046656UL    // bf16 [32][1024]  h double-buf B
// total ~176MB

// ---------------- setup helpers ----------------
__global__ void k_xcat(const float* __restrict__ ce, const float* __restrict__ le,
                       float* __restrict__ xcat) {
  int row = blockIdx.x;  // l*128 + c
  int l = row >> 7, c = row & 127;
  int i = threadIdx.x * 4;
  float4 v;
  if (i < 512) v = *(const float4*)(ce + c * 512 + i);
  else         v = *(const float4*)(le + l * 512 + (i - 512));
  *(float4*)(xcat + (size_t)row * 1024 + i) = v;
}

__global__ void k_cvt(const float* __restrict__ src, int ld, int lc,
                      unsigned short* __restrict__ dst) {
  size_t i = ((size_t)blockIdx.x * 256 + threadIdx.x) * 8;
  size_t r = i >> lc;
  int c = (int)(i & ((1u << lc) - 1));
  const float* s = src + r * (size_t)ld + c;
  float4 v0 = *(const float4*)s;
  float4 v1 = *(const float4*)(s + 4);
  union { unsigned short us[8]; uint4 u; } o;
  o.us[0] = f2bf(v0.x); o.us[1] = f2bf(v0.y); o.us[2] = f2bf(v0.z); o.us[3] = f2bf(v0.w);
  o.us[4] = f2bf(v1.x); o.us[5] = f2bf(v1.y); o.us[6] = f2bf(v1.z); o.us[7] = f2bf(v1.w);
  *(uint4*)(dst + i) = o.u;
}

__global__ void k_transcvt(const float* __restrict__ in, unsigned short* __restrict__ out) {
  __shared__ float t[32][33];
  int c0 = blockIdx.x * 32, r0 = blockIdx.y * 32;
  int tx = threadIdx.x, ty = threadIdx.y;
  for (int i = ty; i < 32; i += 8)
    t[i][tx] = in[(size_t)(r0 + i) * 1024 + c0 + tx];
  __syncthreads();
  for (int i = ty; i < 32; i += 8)
    out[(size_t)(c0 + i) * 1024 + r0 + tx] = f2bf(t[tx][i]);
}

// pack weight rows: src row n (= gate*1024 + unit) -> dst row g*96 + gate*32 + ul
__global__ void k_packw(const float* __restrict__ src, int ld,
                        unsigned short* __restrict__ dst) {
  int n = blockIdx.x;
  int gate = n >> 10, unit = n & 1023;
  int g = unit >> 5, ul = unit & 31;
  size_t drow = (size_t)g * 96 + gate * 32 + ul;
  int k = threadIdx.x * 4;
  float4 v = *(const float4*)(src + (size_t)n * ld + k);
  union { unsigned short us[4]; uint2 u; } o;
  o.us[0] = f2bf(v.x); o.us[1] = f2bf(v.y); o.us[2] = f2bf(v.z); o.us[3] = f2bf(v.w);
  *(uint2*)(dst + drow * 1024 + k) = o.u;
}

// ---------------- fp32 tiled GEMM (setup tables): C=A@W^T ----------------
// P3: write packed [row][col&1023][col>>10] (gate-interleaved)
template <bool BIAS, bool P3 = false>
__global__ __launch_bounds__(256) void k_gemm(
    const float* __restrict__ A, int lda, const float* __restrict__ W, int ldw,
    const float* __restrict__ bias, float* __restrict__ C, int ldc, int K) {
  __shared__ float As[8][128];
  __shared__ float Ws[8][128];
  int tid = threadIdx.x;
  int n0 = blockIdx.x * 128, m0 = blockIdx.y * 128;
  int tx = tid & 15, ty = tid >> 4;
  int lrow = tid >> 1, lseg = (tid & 1) * 4;
  const float* Ap = A + (size_t)(m0 + lrow) * lda + lseg;
  const float* Wp = W + (size_t)(n0 + lrow) * ldw + lseg;
  float acc[8][8];
#pragma unroll
  for (int i = 0; i < 8; ++i)
#pragma unroll
    for (int j = 0; j < 8; ++j) acc[i][j] = 0.f;
  for (int kt = 0; kt < K; kt += 8) {
    float4 av = *(const float4*)(Ap + kt);
    float4 wv = *(const float4*)(Wp + kt);
    __syncthreads();
    As[lseg + 0][lrow] = av.x; As[lseg + 1][lrow] = av.y;
    As[lseg + 2][lrow] = av.z; As[lseg + 3][lrow] = av.w;
    Ws[lseg + 0][lrow] = wv.x; Ws[lseg + 1][lrow] = wv.y;
    Ws[lseg + 2][lrow] = wv.z; Ws[lseg + 3][lrow] = wv.w;
    __syncthreads();
#pragma unroll
    for (int kk = 0; kk < 8; ++kk) {
      float a[8], b[8];
      *(float4*)(a + 0) = *(const float4*)(&As[kk][ty * 8 + 0]);
      *(float4*)(a + 4) = *(const float4*)(&As[kk][ty * 8 + 4]);
      *(float4*)(b + 0) = *(const float4*)(&Ws[kk][tx * 8 + 0]);
      *(float4*)(b + 4) = *(const float4*)(&Ws[kk][tx * 8 + 4]);
#pragma unroll
      for (int i = 0; i < 8; ++i)
#pragma unroll
        for (int j = 0; j < 8; ++j) acc[i][j] = fmaf(a[i], b[j], acc[i][j]);
    }
  }
#pragma unroll
  for (int i = 0; i < 8; ++i) {
    int r = m0 + ty * 8 + i;
#pragma unroll
    for (int j = 0; j < 8; ++j) {
      int c = n0 + tx * 8 + j;
      float v = acc[i][j];
      if (BIAS) v += bias[c];
      if (P3) C[((size_t)r * 1024 + (c & 1023)) * 3 + (c >> 10)] = v;
      else    C[(size_t)r * ldc + c] = v;
    }
  }
}

// ---------------- fused encoder step: gh-GEMM + gates + h update ----------------
// 32 WGs; WG g owns units [g*32,g*32+32) -> packed weight rows [g*96, g*96+96).
// 4 waves split K (256 each); A/B frags read from global (L2); LDS reduce.
__global__ __launch_bounds__(256) void k_encstep(
    const unsigned short* __restrict__ Wp, const float* __restrict__ gitabP,
    const int* __restrict__ sc, const int* __restrict__ sl,
    const float* __restrict__ bh, const unsigned short* __restrict__ hin,
    unsigned short* __restrict__ hout, unsigned short* __restrict__ esb,
    float* __restrict__ hf, int s, int first) {
  __shared__ float red[4][96][36];
  int tid = threadIdx.x, g = blockIdx.x;
  int w = tid >> 6, l = tid & 63;
  int fr = l & 15, fo = l >> 4;
  if (!first) {
    const unsigned short* Ab = hin + (size_t)fr * 1024 + w * 256 + fo * 8;
    const unsigned short* Bp = Wp + ((size_t)g * 96 + fr) * 1024 + w * 256 + fo * 8;
    f32x4 acc[2][6];
#pragma unroll
    for (int i = 0; i < 2; ++i)
#pragma unroll
      for (int j = 0; j < 6; ++j) acc[i][j] = (f32x4){0.f, 0.f, 0.f, 0.f};
#pragma unroll
    for (int ks = 0; ks < 8; ++ks) {
      int ko = ks * 32;
      bf16x8 a0 = *(const bf16x8*)(Ab + ko);
      bf16x8 a1 = *(const bf16x8*)(Ab + 16 * 1024 + ko);
#pragma unroll
      for (int nt = 0; nt < 6; ++nt) {
        bf16x8 bw = *(const bf16x8*)(Bp + (size_t)nt * 16 * 1024 + ko);
        acc[0][nt] = mfma_bf16(a0, bw, acc[0][nt]);
        acc[1][nt] = mfma_bf16(a1, bw, acc[1][nt]);
      }
    }
#pragma unroll
    for (int nt = 0; nt < 6; ++nt)
#pragma unroll
      for (int mt = 0; mt < 2; ++mt)
        *(f32x4*)&red[w][nt * 16 + fr][mt * 16 + fo * 4] = acc[mt][nt];
  }
  __syncthreads();
#pragma unroll
  for (int i = 0; i < 4; ++i) {
    int item = i * 256 + tid;
    int ul = item & 31, b = item >> 5;
    int gu = g * 32 + ul;
    int cl = sl[b * Ss + s] * 128 + sc[b * Ss + s];
    const float* gp = gitabP + ((size_t)cl * 1024 + gu) * 3;
    float gir = gp[0], giz = gp[1], gin = gp[2];
    float ghr = bh[gu], ghz = bh[1024 + gu], ghn = bh[2048 + gu];
    if (!first) {
#pragma unroll
      for (int ww = 0; ww < 4; ++ww) {
        ghr += red[ww][ul][b];
        ghz += red[ww][32 + ul][b];
        ghn += red[ww][64 + ul][b];
      }
    }
    float r = 1.f / (1.f + expf(-(gir + ghr)));
    float z = 1.f / (1.f + expf(-(giz + ghz)));
    float n = tanhf(gin + r * ghn);
    float hold = first ? 0.f : hf[b * 1024 + gu];
    float hv = (1.f - z) * n + z * hold;
    hf[b * 1024 + gu] = hv;
    unsigned short q = f2bf(hv);
    hout[b * 1024 + gu] = q;
    esb[((size_t)b * Ss + s) * 1024 + gu] = q;
  }
}

// ---------------- fused decoder step: gi(ctx)+gh(h) GEMMs + gates ----------------
// waves 0,1: gi = ctx@Wic^T (K halves); waves 2,3: gh = h@Whd^T (K halves).
__global__ __launch_bounds__(256) void k_decstep(
    const unsigned short* __restrict__ WicP, const unsigned short* __restrict__ WhdP,
    const float* __restrict__ dgixtP, const int* __restrict__ tgt,
    const float* __restrict__ bh, const unsigned short* __restrict__ ctxbf,
    const unsigned short* __restrict__ hin, unsigned short* __restrict__ hout,
    float* __restrict__ hf, int t, int first, int usestart) {
  __shared__ float red[4][96][36];
  int tid = threadIdx.x, g = blockIdx.x;
  int w = tid >> 6, l = tid & 63;
  int fr = l & 15, fo = l >> 4;
  int gm = w >> 1, kb = (w & 1) * 512;
  if (!(first && gm)) {
    const unsigned short* A = gm ? hin : ctxbf;
    const unsigned short* Wp = gm ? WhdP : WicP;
    const unsigned short* Ab = A + (size_t)fr * 1024 + kb + fo * 8;
    const unsigned short* Bp = Wp + ((size_t)g * 96 + fr) * 1024 + kb + fo * 8;
    f32x4 acc[2][6];
#pragma unroll
    for (int i = 0; i < 2; ++i)
#pragma unroll
      for (int j = 0; j < 6; ++j) acc[i][j] = (f32x4){0.f, 0.f, 0.f, 0.f};
#pragma unroll
    for (int ks = 0; ks < 16; ++ks) {
      int ko = ks * 32;
      bf16x8 a0 = *(const bf16x8*)(Ab + ko);
      bf16x8 a1 = *(const bf16x8*)(Ab + 16 * 1024 + ko);
#pragma unroll
      for (int nt = 0; nt < 6; ++nt) {
        bf16x8 bw = *(const bf16x8*)(Bp + (size_t)nt * 16 * 1024 + ko);
        acc[0][nt] = mfma_bf16(a0, bw, acc[0][nt]);
        acc[1][nt] = mfma_bf16(a1, bw, acc[1][nt]);
      }
    }
#pragma unroll
    for (int nt = 0; nt < 6; ++nt)
#pragma unroll
      for (int mt = 0; mt < 2; ++mt)
        *(f32x4*)&red[w][nt * 16 + fr][mt * 16 + fo * 4] = acc[mt][nt];
  }
  __syncthreads();
#pragma unroll
  for (int i = 0; i < 4; ++i) {
    int item = i * 256 + tid;
    int ul = item & 31, b = item >> 5;
    int gu = g * 32 + ul;
    int c = usestart ? 1 : tgt[b * Tt + t];
    const float* gp = dgixtP + ((size_t)c * 1024 + gu) * 3;
    float gir = gp[0] + red[0][ul][b] + red[1][ul][b];
    float giz = gp[1] + red[0][32 + ul][b] + red[1][32 + ul][b];
    float gin = gp[2] + red[0][64 + ul][b] + red[1][64 + ul][b];
    float ghr = bh[gu], ghz = bh[1024 + gu], ghn = bh[2048 + gu];
    if (!first) {
      ghr += red[2][ul][b] + red[3][ul][b];
      ghz += red[2][32 + ul][b] + red[3][32 + ul][b];
      ghn += red[2][64 + ul][b] + red[3][64 + ul][b];
    }
    float r = 1.f / (1.f + expf(-(gir + ghr)));
    float z = 1.f / (1.f + expf(-(giz + ghz)));
    float n = tanhf(gin + r * ghn);
    float hold = first ? 0.f : hf[b * 1024 + gu];
    float hv = (1.f - z) * n + z * hold;
    hf[b * 1024 + gu] = hv;
    hout[b * 1024 + gu] = f2bf(hv);
  }
}

// ---------------- attention logits + hc fold ----------------
// 256 blocks: b = id>>3, sc = id&7 (64 s-positions each).
__global__ __launch_bounds__(256) void k_att(const unsigned short* __restrict__ esq,
                                             const float* __restrict__ h,
                                             const float* __restrict__ ctx,
                                             float* __restrict__ attL,
                                             unsigned short* __restrict__ hc) {
  __shared__ float hs[1024];
  int tid = threadIdx.x;
  int b = blockIdx.x >> 3, sc2 = blockIdx.x & 7;
  for (int i = tid; i < 1024; i += 256) hs[i] = h[b * 1024 + i];
  __syncthreads();
  if (sc2 < 4) {
    int j = sc2 * 256 + tid;
    hc[b * 1024 + j] = f2bf(hs[j] + ctx[b * 1024 + j]);
  }
  int sg = tid >> 2, li = tid & 3;
  int s = sc2 * 64 + sg;
  const unsigned short* ep = esq + (size_t)(b * 512 + s) * 1024;
  float acc = 0.f;
#pragma unroll 4
  for (int i = 0; i < 32; ++i) {
    int k = (i * 4 + li) * 8;
    uint4 e = *(const uint4*)(ep + k);
    float4 h0 = *(const float4*)&hs[k];
    float4 h1 = *(const float4*)&hs[k + 4];
    acc += lof(e.x) * h0.x + hif(e.x) * h0.y + lof(e.y) * h0.z + hif(e.y) * h0.w +
           lof(e.z) * h1.x + hif(e.z) * h1.y + lof(e.w) * h1.z + hif(e.w) * h1.w;
  }
  acc += __shfl_xor(acc, 1);
  acc += __shfl_xor(acc, 2);
  if (li == 0) attL[b * 512 + s] = acc;
}

// ---------------- bf16 MFMA GEMM: C[M,N] = A[M,K] @ W[N,K]^T ----------------
template <int EPI, bool RELU, bool BIAS>
__global__ __launch_bounds__(256) void k_bgemm(
    const unsigned short* __restrict__ A, int lda,
    const unsigned short* __restrict__ W, int ldw,
    const float* __restrict__ bias, void* __restrict__ Cout, int ldc, int K,
    const float* __restrict__ avtab, const int* __restrict__ gl,
    const int* __restrict__ gc) {
  __shared__ unsigned short As[128 * APAD];
  __shared__ unsigned short Bs[128 * APAD];
  int tid = threadIdx.x;
  int n0 = blockIdx.x * 128, m0 = blockIdx.y * 128;
  int w = tid >> 6, l = tid & 63;
  int mw = (w & 1) * 64, nw = (w >> 1) * 64;
  int lrow = tid >> 1, lk = (tid & 1) * 16;
  const unsigned short* Ap = A + (size_t)(m0 + lrow) * lda + lk;
  const unsigned short* Wp = W + (size_t)(n0 + lrow) * ldw + lk;
  int fr = l & 15, fk = (l >> 4) * 8;
  f32x4 acc[4][4];
#pragma unroll
  for (int i = 0; i < 4; ++i)
#pragma unroll
    for (int j = 0; j < 4; ++j) acc[i][j] = (f32x4){0.f, 0.f, 0.f, 0.f};
  for (int kt = 0; kt < K; kt += 32) {
    uint4 a0 = *(const uint4*)(Ap + kt);
    uint4 a1 = *(const uint4*)(Ap + kt + 8);
    uint4 b0 = *(const uint4*)(Wp + kt);
    uint4 b1 = *(const uint4*)(Wp + kt + 8);
    __syncthreads();
    *(uint4*)&As[lrow * APAD + lk] = a0;
    *(uint4*)&As[lrow * APAD + lk + 8] = a1;
    *(uint4*)&Bs[lrow * APAD + lk] = b0;
    *(uint4*)&Bs[lrow * APAD + lk + 8] = b1;
    __syncthreads();
    bf16x8 af[4], bfg[4];
#pragma unroll
    for (int i = 0; i < 4; ++i) af[i] = *(const bf16x8*)&As[(mw + i * 16 + fr) * APAD + fk];
#pragma unroll
    for (int j = 0; j < 4; ++j) bfg[j] = *(const bf16x8*)&Bs[(nw + j * 16 + fr) * APAD + fk];
#pragma unroll
    for (int i = 0; i < 4; ++i)
#pragma unroll
      for (int j = 0; j < 4; ++j) acc[i][j] = mfma_bf16(af[i], bfg[j], acc[i][j]);
  }
#pragma unroll
  for (int i = 0; i < 4; ++i)
#pragma unroll
    for (int j = 0; j < 4; ++j) {
      int col = n0 + nw + j * 16 + fr;
#pragma unroll
      for (int r = 0; r < 4; ++r) {
        int row = m0 + mw + i * 16 + (l >> 4) * 4 + r;
        float v = acc[i][j][r];
        if (BIAS) v += bias[col];
        if (RELU) v = fmaxf(v, 0.f);
        if (EPI == 0) {
          ((unsigned short*)Cout)[(size_t)row * ldc + col] = f2bf(v);
        } else if (EPI == 1) {
          int cl = gl[row] * 128 + gc[row];
          ((unsigned short*)Cout)[(size_t)row * ldc + col] =
              f2bf(v + avtab[(size_t)cl * 1024 + col]);
        } else {
          int tt = row >> 5, bb = row & 31;
          ((float*)Cout)[(size_t)bb * (Tt * Vv) + tt * Vv + col] = v;
        }
      }
    }
}

// ---------------- ctx init (ctx = final encoder h) ----------------
__global__ void k_ctxinit(const float* __restrict__ h, float* __restrict__ ctx,
                          unsigned short* __restrict__ ctxbf) {
  int idx = blockIdx.x * 256 + threadIdx.x;
  float v = h[idx];
  ctx[idx] = v;
  ctxbf[idx] = f2bf(v);
}

// ---------------- softmax + ctx = w @ av_bf ----------------
__global__ __launch_bounds__(256) void k_ctxsm(const float* __restrict__ attL,
                                               const unsigned short* __restrict__ av,
                                               float* __restrict__ ctx,
                                               unsigned short* __restrict__ ctxbf) {
  int jt = blockIdx.x, b = blockIdx.y;
  __shared__ float w[512];
  __shared__ float wm[4];
  __shared__ float wsm[4];
  __shared__ float red2[128];
  int tid = threadIdx.x;
  float a0 = attL[b * Ss + tid * 2];
  float a1 = attL[b * Ss + tid * 2 + 1];
  float m = fmaxf(a0, a1);
  for (int d = 1; d < 64; d <<= 1) m = fmaxf(m, __shfl_xor(m, d));
  if ((tid & 63) == 0) wm[tid >> 6] = m;
  __syncthreads();
  m = fmaxf(fmaxf(wm[0], wm[1]), fmaxf(wm[2], wm[3]));
  float e0 = expf(a0 - m), e1 = expf(a1 - m);
  w[tid * 2] = e0;
  w[tid * 2 + 1] = e1;
  float ssum = e0 + e1;
  for (int d = 1; d < 64; d <<= 1) ssum += __shfl_xor(ssum, d);
  if ((tid & 63) == 0) wsm[tid >> 6] = ssum;
  __syncthreads();
  float scale = 1.f / (wsm[0] + wsm[1] + wsm[2] + wsm[3]);
  int j = jt * 128 + (tid & 127);
  int sh = tid >> 7;
  const unsigned short* avp = av + (size_t)(b * Ss + sh * 256) * Hh + j;
  float acc = 0.f;
#pragma unroll 16
  for (int s = 0; s < 256; ++s) acc += w[sh * 256 + s] * bf2f(avp[(size_t)s * Hh]);
  if (sh == 1) red2[tid & 127] = acc;
  __syncthreads();
  if (sh == 0) {
    float v = (acc + red2[tid & 127]) * scale;
    ctx[b * Hh + j] = v;
    ctxbf[b * Hh + j] = f2bf(v);
  }
}

// ---------------- host ----------------
extern "C" void kernel_launch(void* const* d_in, const int* in_sizes, int n_in,
                              void* d_out, int out_size, void* d_ws, size_t ws_size,
                              hipStream_t stream) {
  (void)in_sizes; (void)n_in; (void)out_size; (void)ws_size;
  const int*   src_chars = (const int*)d_in[0];
  const int*   src_langs = (const int*)d_in[1];
  const int*   tgt_chars = (const int*)d_in[2];
  const float* char_emb  = (const float*)d_in[3];
  const float* lang_emb  = (const float*)d_in[4];
  const float* fc_W  = (const float*)d_in[5];
  const float* fc_b  = (const float*)d_in[6];
  const float* enc_Wi = (const float*)d_in[7];
  const float* enc_Wh = (const float*)d_in[8];
  const float* enc_bi = (const float*)d_in[9];
  const float* enc_bh = (const float*)d_in[10];
  const float* dec_Wi = (const float*)d_in[11];
  const float* dec_Wh = (const float*)d_in[12];
  const float* dec_bi = (const float*)d_in[13];
  const float* dec_bh = (const float*)d_in[14];
  const float* Wq  = (const float*)d_in[15];
  const float* Wk  = (const float*)d_in[16];
  const float* Wcs = (const float*)d_in[17];
  const float* W1 = (const float*)d_in[18];
  const float* b1 = (const float*)d_in[19];
  const float* W2 = (const float*)d_in[20];
  const float* b2 = (const float*)d_in[21];
  const float* W3 = (const float*)d_in[22];
  float* out = (float*)d_out;

  char* ws = (char*)d_ws;
  unsigned short* esbf  = (unsigned short*)(ws + O_ESBF);
  unsigned short* esq   = (unsigned short*)(ws + O_ESQ);
  unsigned short* avbf  = (unsigned short*)(ws + O_AVBF);
  unsigned short* hcbf  = (unsigned short*)(ws + O_HCBF);
  unsigned short* WheP  = (unsigned short*)(ws + O_WHE);
  unsigned short* WhdP  = (unsigned short*)(ws + O_WHD);
  unsigned short* WicP  = (unsigned short*)(ws + O_WIC);
  unsigned short* WkB   = (unsigned short*)(ws + O_WKB);
  unsigned short* WqTB  = (unsigned short*)(ws + O_WQT);
  unsigned short* W1B   = (unsigned short*)(ws + O_W1B);
  unsigned short* W2B   = (unsigned short*)(ws + O_W2B);
  unsigned short* W3B   = (unsigned short*)(ws + O_W3B);
  float* xcat   = (float*)(ws + O_XCAT);
  float* embfc  = (float*)(ws + O_EMBFC);
  float* gitab  = (float*)(ws + O_GITAB);
  float* avtab  = (float*)(ws + O_AVTAB);
  float* dgixt  = (float*)(ws + O_DGIXT);
  float* h      = (float*)(ws + O_H);
  unsigned short* he0   = (unsigned short*)(ws + O_HBF);
  unsigned short* he1   = (unsigned short*)(ws + O_HB1);
  float* ctx    = (float*)(ws + O_CTX);
  unsigned short* ctxbf = (unsigned short*)(ws + O_CTXBF);
  float* attL   = (float*)(ws + O_ATTL);
  unsigned short* G1 = esq;   // alias: dead after decoder
  unsigned short* G2 = avbf;  // alias: dead after decoder

  dim3 blk(256);

  // ---- tables (fp32) ----
  k_xcat<<<640, blk, 0, stream>>>(char_emb, lang_emb, xcat);
  k_gemm<true><<<dim3(4, 5), blk, 0, stream>>>(xcat, 1024, fc_W, 1024, fc_b, embfc, 512, 1024);
  k_gemm<true, true><<<dim3(24, 5), blk, 0, stream>>>(embfc, 512, enc_Wi, 512, enc_bi,
                                                      gitab, H3, 512);
  k_gemm<false><<<dim3(8, 5), blk, 0, stream>>>(embfc, 512, Wcs, 512, nullptr, avtab, Hh, 512);
  k_gemm<true, true><<<dim3(24, 1), blk, 0, stream>>>(embfc + 512 * 512, 512, dec_Wi, 1536,
                                                      dec_bi, dgixt, H3, 512);
  // ---- weight conversions / packs ----
  k_packw<<<3072, blk, 0, stream>>>(enc_Wh, 1024, WheP);
  k_packw<<<3072, blk, 0, stream>>>(dec_Wh, 1024, WhdP);
  k_packw<<<3072, blk, 0, stream>>>(dec_Wi + 512, 1536, WicP);
  k_cvt<<<512,  blk, 0, stream>>>(Wk, 1024, 10, WkB);
  k_cvt<<<2048, blk, 0, stream>>>(W1, 1024, 10, W1B);
  k_cvt<<<4096, blk, 0, stream>>>(W2, 4096, 12, W2B);
  k_cvt<<<128,  blk, 0, stream>>>(W3, 2048, 11, W3B);
  k_transcvt<<<dim3(32, 32), dim3(32, 8), 0, stream>>>(Wq, WqTB);

  // ---- encoder scan: one fused kernel per step ----
  for (int s = 0; s < Ss; ++s) {
    const unsigned short* hin = (s & 1) ? he1 : he0;
    unsigned short* hout = (s & 1) ? he0 : he1;
    k_encstep<<<32, blk, 0, stream>>>(WheP, gitab, src_chars, src_langs, enc_bh,
                                      hin, hout, esbf, h, s, s == 0 ? 1 : 0);
  }

  // ---- esq = es @ Wq; av = es @ Wk^T + avtab ----
  k_bgemm<0, false, false><<<dim3(8, 128), blk, 0, stream>>>(
      esbf, 1024, WqTB, 1024, nullptr, esq, 1024, 1024, nullptr, nullptr, nullptr);
  k_bgemm<1, false, false><<<dim3(8, 128), blk, 0, stream>>>(
      esbf, 1024, WkB, 1024, nullptr, avbf, 1024, 1024, avtab, src_langs, src_chars);

  // ---- decoder init: ctx0 + h0 = gru(0, [start_emb, ctx0]) ----
  k_ctxinit<<<128, blk, 0, stream>>>(h, ctx, ctxbf);
  k_decstep<<<32, blk, 0, stream>>>(WicP, WhdP, dgixt, tgt_chars, dec_bh, ctxbf,
                                    he1, he0, h, 0, 1, 1);

  // ---- decoder scan: att+hc / ctxsm / fused gates ----
  for (int t = 0; t < Tt; ++t) {
    k_att<<<256, blk, 0, stream>>>(esq, h, ctx, attL, hcbf + (size_t)t * Bb * Hh);
    if (t == Tt - 1) break;
    k_ctxsm<<<dim3(8, 32), blk, 0, stream>>>(attL, avbf, ctx, ctxbf);
    const unsigned short* hin = (t & 1) ? he1 : he0;
    unsigned short* hout = (t & 1) ? he0 : he1;
    k_decstep<<<32, blk, 0, stream>>>(WicP, WhdP, dgixt, tgt_chars, dec_bh, ctxbf,
                                      hin, hout, h, t, 0, 0);
  }

  // ---- MLP: scores = relu(relu(hc@W1^T+b1)@W2^T+b2)@W3^T ----
  k_bgemm<0, true, true><<<dim3(32, 32), blk, 0, stream>>>(
      hcbf, 1024, W1B, 1024, b1, G1, 4096, 1024, nullptr, nullptr, nullptr);
  k_bgemm<0, true, true><<<dim3(16, 32), blk, 0, stream>>>(
      G1, 4096, W2B, 4096, b2, G2, 2048, 4096, nullptr, nullptr, nullptr);
  k_bgemm<2, false, false><<<dim3(1, 32), blk, 0, stream>>>(
      G2, 2048, W3B, 2048, nullptr, out, 0, 2048, nullptr, nullptr, nullptr);
}